// Round 4
// baseline (101.632 us; speedup 1.0000x reference)
//
#include <hip/hip_runtime.h>

// SigLoss: signature kernel PDE, loss = mean_a( K(X,X) + K(Y,Y) - 2 K(X,Y) ).
// A=256, L=256, D=32. One 64-lane wave per (pair, a) problem; lane owns
// columns j = 4*lane+s. Row recurrence via cumsum; wave scan via DPP.
// R4: dY fragments + double-buffered dX row in NAMED float4 registers —
// R3's VGPR_Count=112 proved the compiler rematerialized dy[4][32] inside
// the row loop (~500 cyc/row stall). All accesses compile-time named now.

#define NROW 255
#define ND 32

#define DPP_ADD(v, ctrl, rmask)                                               \
    ((v) + __int_as_float(__builtin_amdgcn_update_dpp(                        \
               0, __float_as_int(v), (ctrl), (rmask), 0xF, true)))

#define F4SUB(h, l) make_float4((h).x - (l).x, (h).y - (l).y,                 \
                                (h).z - (l).z, (h).w - (l).w)

// Load dY row-diff j = j0+s into 8 named float4 (clamped: row 255 -> 0)
#define LOAD_DY(s)                                                            \
    do {                                                                      \
        const int j = j0 + (s);                                               \
        const int jh = (j + 1 < 256) ? (j + 1) : 255;                         \
        const float4* lo4 = V4 + j * 8;                                       \
        const float4* hi4 = V4 + jh * 8;                                      \
        dy##s##_0 = F4SUB(hi4[0], lo4[0]);                                    \
        dy##s##_1 = F4SUB(hi4[1], lo4[1]);                                    \
        dy##s##_2 = F4SUB(hi4[2], lo4[2]);                                    \
        dy##s##_3 = F4SUB(hi4[3], lo4[3]);                                    \
        dy##s##_4 = F4SUB(hi4[4], lo4[4]);                                    \
        dy##s##_5 = F4SUB(hi4[5], lo4[5]);                                    \
        dy##s##_6 = F4SUB(hi4[6], lo4[6]);                                    \
        dy##s##_7 = F4SUB(hi4[7], lo4[7]);                                    \
    } while (0)

// LDS row i -> named buffer B0..B7 (uniform broadcast, 8x ds_read_b128)
#define LOAD_ROW(B, i)                                                        \
    do {                                                                      \
        const float4* row4 = (const float4*)(dxs + (i) * ND);                 \
        B##0 = row4[0]; B##1 = row4[1]; B##2 = row4[2]; B##3 = row4[3];       \
        B##4 = row4[4]; B##5 = row4[5]; B##6 = row4[6]; B##7 = row4[7];       \
    } while (0)

// 4 FMAs of one float4 pair into alternating accumulators
#define FMA4(ia, ib, r, d)                                                    \
    ia = fmaf((r).x, (d).x, ia); ib = fmaf((r).y, (d).y, ib);                 \
    ia = fmaf((r).z, (d).z, ia); ib = fmaf((r).w, (d).w, ib);

// One chunk c: all 4 column-chains
#define DOT_CHUNK(B, c)                                                       \
    FMA4(i0a, i0b, B##c, dy0_##c)                                             \
    FMA4(i1a, i1b, B##c, dy1_##c)                                             \
    FMA4(i2a, i2b, B##c, dy2_##c)                                             \
    FMA4(i3a, i3b, B##c, dy3_##c)

#define DO_ROW(B)                                                             \
    do {                                                                      \
        /* ib chains init at -1 => m = dot - 1 directly */                    \
        float i0a = 0.f, i0b = -1.f, i1a = 0.f, i1b = -1.f;                   \
        float i2a = 0.f, i2b = -1.f, i3a = 0.f, i3b = -1.f;                   \
        DOT_CHUNK(B, 0) DOT_CHUNK(B, 1) DOT_CHUNK(B, 2) DOT_CHUNK(B, 3)       \
        DOT_CHUNK(B, 4) DOT_CHUNK(B, 5) DOT_CHUNK(B, 6) DOT_CHUNK(B, 7)       \
        float m0 = i0a + i0b, m1 = i1a + i1b;                                 \
        float m2 = i2a + i2b, m3 = i3a + i3b;                                 \
        /* kn: lane i <- lane i+1 (wave_shl:1), lane63 -> 0 */                \
        float kn = __int_as_float(__builtin_amdgcn_update_dpp(                \
            0, __float_as_int(kp0), 0x130, 0xF, 0xF, true));                  \
        float c0 = fmaf(kp0, m0, kp1);                                        \
        float c1 = fmaf(kp1, m1, kp2);                                        \
        float c2 = fmaf(kp2, m2, kp3);                                        \
        float c3 = (lane == 63) ? 0.0f : fmaf(kp3, m3, kn);                   \
        float L0 = c0, L1 = L0 + c1, L2 = L1 + c2;                            \
        float T = L2 + c3;                                                    \
        float S = T;                                                          \
        S = DPP_ADD(S, 0x111, 0xF); /* row_shr:1 */                           \
        S = DPP_ADD(S, 0x112, 0xF); /* row_shr:2 */                           \
        S = DPP_ADD(S, 0x114, 0xF); /* row_shr:4 */                           \
        S = DPP_ADD(S, 0x118, 0xF); /* row_shr:8 */                           \
        S = DPP_ADD(S, 0x142, 0xA); /* row_bcast:15 -> rows 1,3 */            \
        S = DPP_ADD(S, 0x143, 0xC); /* row_bcast:31 -> rows 2,3 */            \
        float E = S - T;                                                      \
        kp0 = 1.0f + E;                                                       \
        kp1 = 1.0f + (E + L0);                                                \
        kp2 = 1.0f + (E + L1);                                                \
        kp3 = 1.0f + (E + L2);                                                \
    } while (0)

__global__ __launch_bounds__(64, 1) void sig_pde(const float* __restrict__ X,
                                                 const float* __restrict__ Y,
                                                 float* __restrict__ partial) {
    const int bid = blockIdx.x;
    const int p = bid >> 8;          // 0=xx, 1=yy, 2=xy
    const int a = bid & 255;
    const float* U = (p == 1) ? Y : X;   // rows (i)
    const float* V = (p == 0) ? X : Y;   // cols (j)
    U += (size_t)a * 256 * ND;
    V += (size_t)a * 256 * ND;
    const int lane = threadIdx.x;

    __shared__ float dxs[NROW * ND];     // 32640 B, dX rows

    // Stage dX = U[i+1]-U[i] into LDS
    const float4* U4 = (const float4*)U;
    float4* dxs4 = (float4*)dxs;
#pragma unroll
    for (int k = 0; k < 32; ++k) {
        int q = lane + (k << 6);         // float4 index
        if (q < 2040) {                  // 2040*4 = 8160 = 255*32
            float4 hi = U4[q + 8];
            float4 lo = U4[q];
            dxs4[q] = F4SUB(hi, lo);
        }
    }

    // dY rows j = 4*lane+s in 32 named float4 (128 VGPR)
    const float4* V4 = (const float4*)V;
    const int j0 = 4 * lane;
    float4 dy0_0, dy0_1, dy0_2, dy0_3, dy0_4, dy0_5, dy0_6, dy0_7;
    float4 dy1_0, dy1_1, dy1_2, dy1_3, dy1_4, dy1_5, dy1_6, dy1_7;
    float4 dy2_0, dy2_1, dy2_2, dy2_3, dy2_4, dy2_5, dy2_6, dy2_7;
    float4 dy3_0, dy3_1, dy3_2, dy3_3, dy3_4, dy3_5, dy3_6, dy3_7;
    LOAD_DY(0); LOAD_DY(1); LOAD_DY(2); LOAD_DY(3);
    __syncthreads();

    // K row state: kp{0..3} = K[i][4*lane+s], row 0 = ones
    float kp0 = 1.0f, kp1 = 1.0f, kp2 = 1.0f, kp3 = 1.0f;

    // Double-buffered dX row in named regs; prefetch next under current FMAs
    float4 a0, a1, a2, a3, a4, a5, a6, a7;
    float4 b0, b1, b2, b3, b4, b5, b6, b7;
    LOAD_ROW(a, 0);
    int i = 0;
#pragma clang loop unroll(disable)
    for (; i + 2 < NROW; i += 2) {       // i = 0,2,...,252
        LOAD_ROW(b, i + 1);
        DO_ROW(a);
        LOAD_ROW(a, i + 2);
        DO_ROW(b);
    }
    DO_ROW(a);                           // row 254 (loaded at i=252)

    if (lane == 63) {
        // kp3 = K[255][255]
        partial[bid] = (p == 2 ? -2.0f : 1.0f) * kp3;
    }
}

__global__ __launch_bounds__(256) void sig_reduce(const float* __restrict__ partial,
                                                  float* __restrict__ out) {
    const int t = threadIdx.x;
    float v = partial[t] + partial[t + 256] + partial[t + 512];
#pragma unroll
    for (int ofs = 32; ofs > 0; ofs >>= 1) v += __shfl_down(v, ofs);
    __shared__ float ws[4];
    if ((t & 63) == 0) ws[t >> 6] = v;
    __syncthreads();
    if (t == 0) out[0] = (ws[0] + ws[1] + ws[2] + ws[3]) * (1.0f / 256.0f);
}

extern "C" void kernel_launch(void* const* d_in, const int* in_sizes, int n_in,
                              void* d_out, int out_size, void* d_ws, size_t ws_size,
                              hipStream_t stream) {
    const float* X = (const float*)d_in[0];
    const float* Y = (const float*)d_in[1];
    float* partial = (float*)d_ws;       // 768 floats
    sig_pde<<<dim3(768), dim3(64), 0, stream>>>(X, Y, partial);
    sig_reduce<<<dim3(1), dim3(256), 0, stream>>>(partial, (float*)d_out);
}

// Round 5
// 79.534 us; speedup vs baseline: 1.2778x; 1.2778x over previous
//
#include <hip/hip_runtime.h>

// SigLoss: signature kernel PDE, loss = mean_a( K(X,X) + K(Y,Y) - 2 K(X,Y) ).
// A=256, L=256, D=32. One 64-lane wave per (pair, a) problem; lane owns
// columns j = 4*lane+s. Row recurrence via cumsum; wave scan via DPP.
// R5 = R3 (best, 86us) + asm-pin of the 128 dY registers: R3/R4 VGPR counts
// (112/132) proved the compiler rematerializes the dY global loads every row
// (~500 cyc/row stall). asm volatile("":"+v"(x)) makes each value opaque so
// it CANNOT be rematerialized and must stay resident across the row loop.

#define NROW 255
#define ND 32

// DPP-based add-scan step: v += dpp_move(v). bound_ctrl=1 -> invalid lanes
// contribute 0; row_mask gates which 16-lane rows get written (others add 0).
#define DPP_ADD(v, ctrl, rmask)                                               \
    ((v) + __int_as_float(__builtin_amdgcn_update_dpp(                        \
               0, __float_as_int(v), (ctrl), (rmask), 0xF, true)))

// Opaque touch: forbids rematerialization, forces register residency.
#define PIN(x) asm volatile("" : "+v"(x))

__global__ __launch_bounds__(64, 1) void sig_pde(const float* __restrict__ X,
                                                 const float* __restrict__ Y,
                                                 float* __restrict__ partial) {
    const int bid = blockIdx.x;
    const int p = bid >> 8;          // 0=xx, 1=yy, 2=xy
    const int a = bid & 255;
    const float* U = (p == 1) ? Y : X;   // rows (i)
    const float* V = (p == 0) ? X : Y;   // cols (j)
    U += (size_t)a * 256 * ND;
    V += (size_t)a * 256 * ND;
    const int lane = threadIdx.x;

    __shared__ float dxs[NROW * ND];     // 32640 B, dX rows

    // Stage dX = U[i+1]-U[i] into LDS
    const float4* U4 = (const float4*)U;
    float4* dxs4 = (float4*)dxs;
#pragma unroll
    for (int k = 0; k < 32; ++k) {
        int q = lane + (k << 6);         // float4 index
        if (q < 2040) {                  // 2040*4 = 8160 = 255*32
            float4 hi = U4[q + 8];
            float4 lo = U4[q];
            dxs4[q] = make_float4(hi.x - lo.x, hi.y - lo.y, hi.z - lo.z, hi.w - lo.w);
        }
    }

    // dY rows j = 4*lane + s into registers (128 VGPR)
    float dy[4][ND];
    const float4* V4 = (const float4*)V;
#pragma unroll
    for (int s = 0; s < 4; ++s) {
        int j = 4 * lane + s;
        if (j < NROW) {
#pragma unroll
            for (int c = 0; c < 8; ++c) {
                float4 hi = V4[(j + 1) * 8 + c];
                float4 lo = V4[j * 8 + c];
                dy[s][4 * c + 0] = hi.x - lo.x;
                dy[s][4 * c + 1] = hi.y - lo.y;
                dy[s][4 * c + 2] = hi.z - lo.z;
                dy[s][4 * c + 3] = hi.w - lo.w;
            }
        } else {                          // only lane 63, s=3 (j=255)
#pragma unroll
            for (int d = 0; d < ND; ++d) dy[s][d] = 0.0f;
        }
    }
    // Pin every dY value: opaque to the compiler -> cannot rematerialize,
    // must remain resident in VGPRs for the whole row loop.
#pragma unroll
    for (int s = 0; s < 4; ++s)
#pragma unroll
        for (int d = 0; d < ND; ++d) PIN(dy[s][d]);
    __syncthreads();

    // K row state: kp{0..3} = K[i][4*lane+s], init row 0 = all ones
    float kp0 = 1.0f, kp1 = 1.0f, kp2 = 1.0f, kp3 = 1.0f;

    // Load dX row i from LDS into registers (uniform broadcast, 8x b128)
    auto load_row = [&](int i, float (&dst)[ND]) {
        const float4* row4 = (const float4*)(dxs + i * ND);
#pragma unroll
        for (int c = 0; c < 8; ++c) {
            float4 v = row4[c];
            dst[4 * c + 0] = v.x; dst[4 * c + 1] = v.y;
            dst[4 * c + 2] = v.z; dst[4 * c + 3] = v.w;
        }
    };

    auto do_row = [&](const float (&dxr)[ND]) {
        // inc[s] = dot(dX[i], dY[4*lane+s]) — 8 independent FMA chains
        float ia0 = 0.f, ia1 = 0.f, ia2 = 0.f, ia3 = 0.f;
        float ib0 = 0.f, ib1 = 0.f, ib2 = 0.f, ib3 = 0.f;
#pragma unroll
        for (int d = 0; d < ND; d += 2) {
            ia0 = fmaf(dxr[d], dy[0][d], ia0);
            ib0 = fmaf(dxr[d + 1], dy[0][d + 1], ib0);
            ia1 = fmaf(dxr[d], dy[1][d], ia1);
            ib1 = fmaf(dxr[d + 1], dy[1][d + 1], ib1);
            ia2 = fmaf(dxr[d], dy[2][d], ia2);
            ib2 = fmaf(dxr[d + 1], dy[2][d + 1], ib2);
            ia3 = fmaf(dxr[d], dy[3][d], ia3);
            ib3 = fmaf(dxr[d + 1], dy[3][d + 1], ib3);
        }
        float inc0 = ia0 + ib0, inc1 = ia1 + ib1;
        float inc2 = ia2 + ib2, inc3 = ia3 + ib3;

        // c[j] = K[i][j+1] + K[i][j]*(inc-1); K[i][4l+4] is next lane's kp0.
        // kn via DPP wave_shl:1 (0x130): lane i <- lane i+1, lane 63 -> 0.
        float kn = __int_as_float(__builtin_amdgcn_update_dpp(
            0, __float_as_int(kp0), 0x130 /*wave_shl:1*/, 0xF, 0xF, true));
        float c0 = kp1 + kp0 * (inc0 - 1.0f);
        float c1 = kp2 + kp1 * (inc1 - 1.0f);
        float c2 = kp3 + kp2 * (inc2 - 1.0f);
        float c3 = (lane == 63) ? 0.0f : kn + kp3 * (inc3 - 1.0f);

        // local inclusive sums + DPP wave scan of lane totals
        float L0 = c0, L1 = L0 + c1, L2 = L1 + c2;
        float T = L2 + c3;
        float S = T;
        S = DPP_ADD(S, 0x111, 0xF);  // row_shr:1
        S = DPP_ADD(S, 0x112, 0xF);  // row_shr:2
        S = DPP_ADD(S, 0x114, 0xF);  // row_shr:4
        S = DPP_ADD(S, 0x118, 0xF);  // row_shr:8
        S = DPP_ADD(S, 0x142, 0xA);  // row_bcast:15 -> rows 1,3
        S = DPP_ADD(S, 0x143, 0xC);  // row_bcast:31 -> rows 2,3
        float E = S - T;             // exclusive scan: sum c[0..4*lane-1]
        kp0 = 1.0f + E;
        kp1 = 1.0f + E + L0;
        kp2 = 1.0f + E + L1;
        kp3 = 1.0f + E + L2;
    };

    // Software-pipelined row loop: prefetch row i+1's LDS reads under row i's
    // FMAs (double-buffered registers, all indices compile-time constant).
    float bufA[ND], bufB[ND];
    load_row(0, bufA);
    int i = 0;
    for (; i + 2 <= NROW; i += 2) {
        load_row(i + 1, bufB);
        do_row(bufA);
        if (i + 2 < NROW) load_row(i + 2, bufA);
        do_row(bufB);
    }
    if (i < NROW) do_row(bufA);      // row 254

    if (lane == 63) {
        // kp3 = K[255][255]
        partial[bid] = (p == 2 ? -2.0f : 1.0f) * kp3;
    }
}

__global__ __launch_bounds__(256) void sig_reduce(const float* __restrict__ partial,
                                                  float* __restrict__ out) {
    const int t = threadIdx.x;
    float v = partial[t] + partial[t + 256] + partial[t + 512];
#pragma unroll
    for (int ofs = 32; ofs > 0; ofs >>= 1) v += __shfl_down(v, ofs);
    __shared__ float ws[4];
    if ((t & 63) == 0) ws[t >> 6] = v;
    __syncthreads();
    if (t == 0) out[0] = (ws[0] + ws[1] + ws[2] + ws[3]) * (1.0f / 256.0f);
}

extern "C" void kernel_launch(void* const* d_in, const int* in_sizes, int n_in,
                              void* d_out, int out_size, void* d_ws, size_t ws_size,
                              hipStream_t stream) {
    const float* X = (const float*)d_in[0];
    const float* Y = (const float*)d_in[1];
    float* partial = (float*)d_ws;       // 768 floats
    sig_pde<<<dim3(768), dim3(64), 0, stream>>>(X, Y, partial);
    sig_reduce<<<dim3(1), dim3(256), 0, stream>>>(partial, (float*)d_out);
}